// Round 1
// baseline (1040.251 us; speedup 1.0000x reference)
//
#include <hip/hip_runtime.h>

#define B_ 8
#define N_ 2048
#define D_ 131
#define DP 132
#define BN (B_ * N_)
#define TQ 32
#define TK 32

__device__ __forceinline__ float dot4f(const float4& a, const float4& b) {
  return a.x * b.x + a.y * b.y + a.z * b.z + a.w * b.w;
}

#define FMA4(o, p, v)                                                          \
  do {                                                                         \
    o.x = fmaf(p, v.x, o.x);                                                   \
    o.y = fmaf(p, v.y, o.y);                                                   \
    o.z = fmaf(p, v.z, o.z);                                                   \
    o.w = fmaf(p, v.w, o.w);                                                   \
  } while (0)

// ---------------------------------------------------------------------------
// Kernel 0: pad W (131x131, rows 524B -> misaligned) into [131][132] fp32 in ws
// so proj can do aligned float4 reads. grid(3), block(256).
// ---------------------------------------------------------------------------
__global__ void pad_w_kernel(const float* __restrict__ Wq,
                             const float* __restrict__ Wk,
                             const float* __restrict__ Wv,
                             float* __restrict__ wp) {
  const int p = blockIdx.x;
  const float* __restrict__ W = (p == 0) ? Wq : (p == 1) ? Wk : Wv;
  float* __restrict__ o = wp + (size_t)p * D_ * DP;
  for (int i = threadIdx.x; i < D_ * DP; i += blockDim.x) {
    const int e = i / DP;
    const int d = i - e * DP;
    o[i] = (d < D_) ? W[e * D_ + d] : 0.f;
  }
}

// ---------------------------------------------------------------------------
// Kernel 1: projections. out[row][e] = bias[e] + sum_d x[row][d] * W[e][d],
// zero-padded to DP cols. grid(BN/64, 3), block(256).
// x tile (64x132) staged in LDS; padded W read from global (L2-resident 69KB,
// same-address lanes coalesce). 4 rows x 9 cols register micro-tile.
// ---------------------------------------------------------------------------
__global__ __launch_bounds__(256) void proj_kernel(
    const float* __restrict__ q, const float* __restrict__ k,
    const float* __restrict__ v, const float* __restrict__ bq,
    const float* __restrict__ bk, const float* __restrict__ bv,
    const float* __restrict__ wp, float* __restrict__ ws) {
  const int p = blockIdx.y;
  const float* __restrict__ x = (p == 0) ? q : (p == 1) ? k : v;
  const float* __restrict__ bias = (p == 0) ? bq : (p == 1) ? bk : bv;
  const float* __restrict__ Wp = wp + (size_t)p * D_ * DP;
  float* __restrict__ out = ws + (size_t)p * BN * DP;

  __shared__ float sX[64][DP];
  __shared__ float sB[DP];

  const int tid = threadIdx.x;
  const int lane = tid & 63;
  const int wv_ = tid >> 6;
  const int r0 = blockIdx.x * 64;

  for (int r = wv_; r < 64; r += 4) {
    const float* xr = x + (size_t)(r0 + r) * D_;
    for (int d = lane; d < D_; d += 64) sX[r][d] = xr[d];
    if (lane == 0) sX[r][D_] = 0.f;
  }
  if (tid < D_) sB[tid] = bias[tid];
  if (tid == D_) sB[D_] = 0.f;
  __syncthreads();

  const int rg = tid >> 4;  // 0..15 -> rows rg + 16*i
  const int eg = tid & 15;  // 0..15 -> cols eg + 16*j

  float acc[4][9];
#pragma unroll
  for (int i = 0; i < 4; ++i)
#pragma unroll
    for (int j = 0; j < 9; ++j) acc[i][j] = 0.f;

  const float4* sXf = reinterpret_cast<const float4*>(&sX[0][0]);
  const float4* Wf = reinterpret_cast<const float4*>(Wp);

  for (int d4 = 0; d4 < DP / 4; ++d4) {
    float4 xv[4];
#pragma unroll
    for (int i = 0; i < 4; ++i) xv[i] = sXf[(rg + 16 * i) * (DP / 4) + d4];
#pragma unroll
    for (int j = 0; j < 9; ++j) {
      const int e = eg + 16 * j;
      if (e >= D_) continue;
      const float4 wvv = Wf[e * (DP / 4) + d4];
#pragma unroll
      for (int i = 0; i < 4; ++i) acc[i][j] += dot4f(xv[i], wvv);
    }
  }

#pragma unroll
  for (int j = 0; j < 9; ++j) {
    const int e = eg + 16 * j;
    if (e >= DP) continue;  // e in [0,131]; 131 is the zero pad column
    const float bval = (e < D_) ? sB[e] : 0.f;
#pragma unroll
    for (int i = 0; i < 4; ++i) {
      const int r = rg + 16 * i;
      const float val = (e < D_) ? (acc[i][j] + bval) : 0.f;
      out[(size_t)(r0 + r) * DP + e] = val;
    }
  }
}

// ---------------------------------------------------------------------------
// Kernel 2: flash attention, fp32. grid(N/TQ, B), block(256), ~55.7KB LDS
// (2 blocks/CU). Per key tile: S=QK^T (2x2 micro, float4 LDS reads) ->
// wave-parallel online softmax (8 lanes/row) -> PV accumulate in registers.
// ---------------------------------------------------------------------------
__global__ __launch_bounds__(256) void attn_kernel(const float* __restrict__ ws,
                                                   float* __restrict__ out) {
  const float* __restrict__ Qp = ws;
  const float* __restrict__ Kp = ws + (size_t)BN * DP;
  const float* __restrict__ Vp = ws + (size_t)2 * BN * DP;

  const int b = blockIdx.y;
  const int q0 = blockIdx.x * TQ;

  const float* Qb = Qp + ((size_t)b * N_ + q0) * DP;
  const float* Kb = Kp + (size_t)b * N_ * DP;
  const float* Vb = Vp + (size_t)b * N_ * DP;

  __shared__ float sQ[TQ][DP];
  __shared__ float sK[TK][DP];
  __shared__ float sV[TK][DP];
  __shared__ float sS[TQ][TK + 1];  // +1 pad: de-conflict the 4-lane stores
  __shared__ float m_s[TQ], l_s[TQ], f_s[TQ];

  const int tid = threadIdx.x;

  {
    const float4* g = reinterpret_cast<const float4*>(Qb);
    float4* s = reinterpret_cast<float4*>(&sQ[0][0]);
    for (int i = tid; i < TQ * DP / 4; i += 256) s[i] = g[i];
  }
  if (tid < TQ) {
    m_s[tid] = -1e30f;
    l_s[tid] = 0.f;
  }

  // O accumulators: rows {qg, qg+16}, col chunks {4dg..}, {64+4dg..},
  // and (dg==0 only) {128..131}.
  float4 o0[3], o1[3];
#pragma unroll
  for (int c = 0; c < 3; ++c) {
    o0[c] = make_float4(0.f, 0.f, 0.f, 0.f);
    o1[c] = make_float4(0.f, 0.f, 0.f, 0.f);
  }

  const int qp = tid >> 4;  // 0..15
  const int kp = tid & 15;  // 0..15
  const float ISC = 0.08737040566610379f;  // 1/sqrt(131)

  const float4* sQf = reinterpret_cast<const float4*>(&sQ[0][0]);
  const float4* sKf = reinterpret_cast<const float4*>(&sK[0][0]);
  const float4* sVf = reinterpret_cast<const float4*>(&sV[0][0]);

  for (int kt = 0; kt < N_ / TK; ++kt) {
    __syncthreads();  // previous PV done before overwriting sK/sV
    {
      const float4* gk =
          reinterpret_cast<const float4*>(Kb + (size_t)kt * TK * DP);
      const float4* gv =
          reinterpret_cast<const float4*>(Vb + (size_t)kt * TK * DP);
      float4* sk = reinterpret_cast<float4*>(&sK[0][0]);
      float4* sv = reinterpret_cast<float4*>(&sV[0][0]);
      for (int i = tid; i < TK * DP / 4; i += 256) {
        sk[i] = gk[i];
        sv[i] = gv[i];
      }
    }
    __syncthreads();

    // ---- S = Q K^T (rows {qp,qp+16} x cols {kp,kp+16}) ----
    float a00 = 0.f, a01 = 0.f, a10 = 0.f, a11 = 0.f;
#pragma unroll
    for (int d4 = 0; d4 < DP / 4; ++d4) {
      const float4 qv0 = sQf[qp * (DP / 4) + d4];
      const float4 qv1 = sQf[(qp + 16) * (DP / 4) + d4];
      const float4 kv0 = sKf[kp * (DP / 4) + d4];
      const float4 kv1 = sKf[(kp + 16) * (DP / 4) + d4];
      a00 += dot4f(qv0, kv0);
      a01 += dot4f(qv0, kv1);
      a10 += dot4f(qv1, kv0);
      a11 += dot4f(qv1, kv1);
    }
    sS[qp][kp] = a00 * ISC;
    sS[qp][kp + 16] = a01 * ISC;
    sS[qp + 16][kp] = a10 * ISC;
    sS[qp + 16][kp + 16] = a11 * ISC;
    __syncthreads();

    // ---- online softmax: 32 rows x 8 lanes ----
    {
      const int row = tid >> 3, g = tid & 7;
      const float s0 = sS[row][g], s1 = sS[row][g + 8];
      const float s2 = sS[row][g + 16], s3 = sS[row][g + 24];
      float tmax = fmaxf(fmaxf(s0, s1), fmaxf(s2, s3));
      tmax = fmaxf(tmax, __shfl_xor(tmax, 1));
      tmax = fmaxf(tmax, __shfl_xor(tmax, 2));
      tmax = fmaxf(tmax, __shfl_xor(tmax, 4));
      const float mold = m_s[row];
      const float mnew = fmaxf(mold, tmax);
      const float p0 = __expf(s0 - mnew), p1 = __expf(s1 - mnew);
      const float p2 = __expf(s2 - mnew), p3 = __expf(s3 - mnew);
      float ps = p0 + p1 + p2 + p3;
      ps += __shfl_xor(ps, 1);
      ps += __shfl_xor(ps, 2);
      ps += __shfl_xor(ps, 4);
      sS[row][g] = p0;
      sS[row][g + 8] = p1;
      sS[row][g + 16] = p2;
      sS[row][g + 24] = p3;
      if (g == 0) {
        const float f = __expf(mold - mnew);
        f_s[row] = f;
        l_s[row] = l_s[row] * f + ps;
        m_s[row] = mnew;
      }
    }
    __syncthreads();

    // ---- PV accumulate (rescale-then-add) ----
    {
      const int qg = qp, dg = kp;
      const float f0 = f_s[qg], f1 = f_s[qg + 16];
#pragma unroll
      for (int c = 0; c < 3; ++c) {
        o0[c].x *= f0; o0[c].y *= f0; o0[c].z *= f0; o0[c].w *= f0;
        o1[c].x *= f1; o1[c].y *= f1; o1[c].z *= f1; o1[c].w *= f1;
      }
      for (int kj = 0; kj < TK; ++kj) {
        const float pa = sS[qg][kj];
        const float pb = sS[qg + 16][kj];
        const float4 v0 = sVf[kj * (DP / 4) + dg];
        const float4 v1 = sVf[kj * (DP / 4) + 16 + dg];
        FMA4(o0[0], pa, v0);
        FMA4(o0[1], pa, v1);
        FMA4(o1[0], pb, v0);
        FMA4(o1[1], pb, v1);
        if (dg == 0) {
          const float4 v2 = sVf[kj * (DP / 4) + 32];
          FMA4(o0[2], pa, v2);
          FMA4(o1[2], pb, v2);
        }
      }
    }
  }

  // ---- epilogue: normalize and store (cols 0..130 only) ----
  {
    const int qg = qp, dg = kp;
    const float il0 = 1.f / l_s[qg];
    const float il1 = 1.f / l_s[qg + 16];
    float* orow0 = out + ((size_t)b * N_ + q0 + qg) * D_;
    float* orow1 = out + ((size_t)b * N_ + q0 + qg + 16) * D_;
    orow0[4 * dg + 0] = o0[0].x * il0;
    orow0[4 * dg + 1] = o0[0].y * il0;
    orow0[4 * dg + 2] = o0[0].z * il0;
    orow0[4 * dg + 3] = o0[0].w * il0;
    orow0[64 + 4 * dg + 0] = o0[1].x * il0;
    orow0[64 + 4 * dg + 1] = o0[1].y * il0;
    orow0[64 + 4 * dg + 2] = o0[1].z * il0;
    orow0[64 + 4 * dg + 3] = o0[1].w * il0;
    orow1[4 * dg + 0] = o1[0].x * il1;
    orow1[4 * dg + 1] = o1[0].y * il1;
    orow1[4 * dg + 2] = o1[0].z * il1;
    orow1[4 * dg + 3] = o1[0].w * il1;
    orow1[64 + 4 * dg + 0] = o1[1].x * il1;
    orow1[64 + 4 * dg + 1] = o1[1].y * il1;
    orow1[64 + 4 * dg + 2] = o1[1].z * il1;
    orow1[64 + 4 * dg + 3] = o1[1].w * il1;
    if (dg == 0) {
      orow0[128] = o0[2].x * il0;
      orow0[129] = o0[2].y * il0;
      orow0[130] = o0[2].z * il0;
      orow1[128] = o1[2].x * il1;
      orow1[129] = o1[2].y * il1;
      orow1[130] = o1[2].z * il1;
    }
  }
}

extern "C" void kernel_launch(void* const* d_in, const int* in_sizes, int n_in,
                              void* d_out, int out_size, void* d_ws,
                              size_t ws_size, hipStream_t stream) {
  const float* q = (const float*)d_in[0];
  const float* k = (const float*)d_in[1];
  const float* v = (const float*)d_in[2];
  const float* Wq = (const float*)d_in[3];
  const float* bq = (const float*)d_in[4];
  const float* Wk = (const float*)d_in[5];
  const float* bk = (const float*)d_in[6];
  const float* Wv = (const float*)d_in[7];
  const float* bv = (const float*)d_in[8];
  float* out = (float*)d_out;
  float* ws = (float*)d_ws;

  // ws layout (floats): Qp[BN*DP] | Kp[BN*DP] | Vp[BN*DP] | Wp[3*D_*DP]
  float* wp = ws + (size_t)3 * BN * DP;

  hipLaunchKernelGGL(pad_w_kernel, dim3(3), dim3(256), 0, stream, Wq, Wk, Wv,
                     wp);
  hipLaunchKernelGGL(proj_kernel, dim3(BN / 64, 3), dim3(256), 0, stream, q, k,
                     v, bq, bk, bv, wp, ws);
  hipLaunchKernelGGL(attn_kernel, dim3(N_ / TQ, B_), dim3(256), 0, stream, ws,
                     out);
}

// Round 2
// 179.341 us; speedup vs baseline: 5.8004x; 5.8004x over previous
//
#include <hip/hip_runtime.h>

#define B_ 8
#define N_ 2048
#define D_ 131
#define DP 132        // fp32 padded dim for W (proj compute, unchanged)
#define Dp16 160      // bf16 padded dim (5 chunks of 32)
#define BN (B_ * N_)
#define KB 64         // keys per tile
#define QW 32         // queries per wave
#define DT 9          // d-tiles of 16 for PV (covers d<144 >= 131)
#define VROWS 144
#define VSTR 72       // sVt row stride (ushort) - bank-even
#define PSTR 72       // sP row stride (ushort) - bank-even

typedef __attribute__((ext_vector_type(8))) short s16x8;
typedef __attribute__((ext_vector_type(4))) float f32x4;

__device__ __forceinline__ float dot4f(const float4& a, const float4& b) {
  return a.x * b.x + a.y * b.y + a.z * b.z + a.w * b.w;
}

// round-to-nearest-even f32 -> bf16 (values are finite, non-NaN here)
__device__ __forceinline__ ushort f2bf(float x) {
  uint u = __float_as_uint(x);
  u += 0x7fffu + ((u >> 16) & 1u);
  return (ushort)(u >> 16);
}
__device__ __forceinline__ uint bfpair(float a, float b) {
  uint ua = __float_as_uint(a);
  ua += 0x7fffu + ((ua >> 16) & 1u);
  uint ub = __float_as_uint(b);
  ub += 0x7fffu + ((ub >> 16) & 1u);
  return (ua >> 16) | (ub & 0xffff0000u);
}

// ---------------------------------------------------------------------------
// Kernel 0: pad W rows (131 fp32, misaligned) to [131][132] fp32. grid(3).
// ---------------------------------------------------------------------------
__global__ void pad_w_kernel(const float* __restrict__ Wq,
                             const float* __restrict__ Wk,
                             const float* __restrict__ Wv,
                             float* __restrict__ wp) {
  const int p = blockIdx.x;
  const float* __restrict__ W = (p == 0) ? Wq : (p == 1) ? Wk : Wv;
  float* __restrict__ o = wp + (size_t)p * D_ * DP;
  for (int i = threadIdx.x; i < D_ * DP; i += blockDim.x) {
    const int e = i / DP;
    const int d = i - e * DP;
    o[i] = (d < D_) ? W[e * D_ + d] : 0.f;
  }
}

// ---------------------------------------------------------------------------
// Kernel 1: projections (fp32 compute). Emits bf16:
//   p=0: Qb16[b][n][160], scaled by 1/sqrt(131), zero-padded d>=131
//   p=1: Kb16[b][n][160], zero-padded
//   p=2: Vt  [b][d][2048] transposed, rows 131..143 zeroed
// ---------------------------------------------------------------------------
__global__ __launch_bounds__(256) void proj_kernel(
    const float* __restrict__ q, const float* __restrict__ k,
    const float* __restrict__ v, const float* __restrict__ bq,
    const float* __restrict__ bk, const float* __restrict__ bv,
    const float* __restrict__ wp, ushort* __restrict__ Qb16,
    ushort* __restrict__ Kb16, ushort* __restrict__ Vt) {
  const int p = blockIdx.y;
  const float* __restrict__ x = (p == 0) ? q : (p == 1) ? k : v;
  const float* __restrict__ bias = (p == 0) ? bq : (p == 1) ? bk : bv;
  const float* __restrict__ Wp = wp + (size_t)p * D_ * DP;

  __shared__ float sX[64][DP];
  __shared__ float sB[DP];

  const int tid = threadIdx.x;
  const int lane = tid & 63;
  const int wv_ = tid >> 6;
  const int r0 = blockIdx.x * 64;

  for (int r = wv_; r < 64; r += 4) {
    const float* xr = x + (size_t)(r0 + r) * D_;
    for (int d = lane; d < D_; d += 64) sX[r][d] = xr[d];
    if (lane == 0) sX[r][D_] = 0.f;
  }
  if (tid < D_) sB[tid] = bias[tid];
  if (tid == D_) sB[D_] = 0.f;
  __syncthreads();

  const int rg = tid >> 4;
  const int eg = tid & 15;

  float acc[4][9];
#pragma unroll
  for (int i = 0; i < 4; ++i)
#pragma unroll
    for (int j = 0; j < 9; ++j) acc[i][j] = 0.f;

  const float4* sXf = reinterpret_cast<const float4*>(&sX[0][0]);
  const float4* Wf = reinterpret_cast<const float4*>(Wp);

  for (int d4 = 0; d4 < DP / 4; ++d4) {
    float4 xv[4];
#pragma unroll
    for (int i = 0; i < 4; ++i) xv[i] = sXf[(rg + 16 * i) * (DP / 4) + d4];
#pragma unroll
    for (int j = 0; j < 9; ++j) {
      const int e = eg + 16 * j;
      if (e >= D_) continue;
      const float4 wvv = Wf[e * (DP / 4) + d4];
#pragma unroll
      for (int i = 0; i < 4; ++i) acc[i][j] += dot4f(xv[i], wvv);
    }
  }

  const float ISC = 0.08737040566610379f;  // 1/sqrt(131)

#pragma unroll
  for (int j = 0; j < 9; ++j) {
    const int e = eg + 16 * j;
    if (e >= D_) continue;
    const float bval = sB[e];
#pragma unroll
    for (int i = 0; i < 4; ++i) {
      const int rn = r0 + rg + 16 * i;  // global row (b*2048+n)
      const float val = acc[i][j] + bval;
      if (p == 0) {
        Qb16[(size_t)rn * Dp16 + e] = f2bf(val * ISC);
      } else if (p == 1) {
        Kb16[(size_t)rn * Dp16 + e] = f2bf(val);
      } else {
        const int bb = rn >> 11, nn = rn & 2047;
        Vt[((size_t)bb * 160 + e) * N_ + nn] = f2bf(val);
      }
    }
  }

  if (p == 0 || p == 1) {
    ushort* arr = (p == 0) ? Qb16 : Kb16;
    for (int idx = tid; idx < 64 * 29; idx += 256) {
      const int r = idx / 29;
      const int e = 131 + (idx - r * 29);
      arr[(size_t)(r0 + r) * Dp16 + e] = 0;
    }
  } else {
    for (int idx = tid; idx < 64 * 13; idx += 256) {
      const int r = idx / 13;
      const int e = 131 + (idx - r * 13);
      const int rn = r0 + r;
      Vt[((size_t)(rn >> 11) * 160 + e) * N_ + (rn & 2047)] = 0;
    }
  }
}

// ---------------------------------------------------------------------------
// Kernel 2: MFMA flash attention. grid(N/64, B), block(128) = 2 waves.
// Wave w: 32 queries. Swapped QK^T: S^T = mfma(Kfrag, Qfrag) so softmax rows
// are lane-local (query = lane&15). P -> wave-private LDS -> PV A-frags.
// ---------------------------------------------------------------------------
__global__ __launch_bounds__(128) void attn_mfma(
    const ushort* __restrict__ Qg, const ushort* __restrict__ Kg,
    const ushort* __restrict__ Vtg, float* __restrict__ out) {
  const int b = blockIdx.y;
  const int q0 = blockIdx.x * 64;
  const int tid = threadIdx.x;
  const int w = tid >> 6;
  const int l = tid & 63;
  const int lr = l & 15;
  const int lg = l >> 4;

  __shared__ ushort sK[KB * Dp16];
  __shared__ ushort sVt[VROWS * VSTR];
  __shared__ ushort sP[2][QW * PSTR];

  s16x8 qf[2][5];
  {
    const ushort* Qbase = Qg + (size_t)(b * N_ + q0 + w * QW) * Dp16;
#pragma unroll
    for (int qt = 0; qt < 2; ++qt)
#pragma unroll
      for (int ch = 0; ch < 5; ++ch)
        qf[qt][ch] = *(const s16x8*)(Qbase + (size_t)(qt * 16 + lr) * Dp16 +
                                     ch * 32 + lg * 8);
  }

  f32x4 o[2][DT];
#pragma unroll
  for (int qt = 0; qt < 2; ++qt)
#pragma unroll
    for (int dt = 0; dt < DT; ++dt) o[qt][dt] = (f32x4){0.f, 0.f, 0.f, 0.f};

  float mreg[2] = {-1e30f, -1e30f};
  float lreg[2] = {0.f, 0.f};

  const ushort* Kb = Kg + (size_t)b * N_ * Dp16;
  const ushort* Vb = Vtg + (size_t)b * 160 * N_;

  for (int kt = 0; kt < N_ / KB; ++kt) {
    __syncthreads();
    {
      const uint4* src = (const uint4*)(Kb + (size_t)kt * KB * Dp16);
      uint4* dst = (uint4*)sK;
#pragma unroll
      for (int i = 0; i < 10; ++i) dst[i * 128 + tid] = src[i * 128 + tid];
    }
    {
      const int dr = tid >> 3;
      const int c8 = (tid & 7) * 8;
#pragma unroll
      for (int i = 0; i < 9; ++i) {
        const int d = i * 16 + dr;
        const uint4 val = *(const uint4*)(Vb + (size_t)d * N_ + kt * KB + c8);
        *(uint4*)(sVt + (size_t)d * VSTR + c8) = val;
      }
    }
    __syncthreads();

    f32x4 s[4][2];
#pragma unroll
    for (int a = 0; a < 4; ++a)
#pragma unroll
      for (int qt = 0; qt < 2; ++qt) s[a][qt] = (f32x4){0.f, 0.f, 0.f, 0.f};

#pragma unroll
    for (int ch = 0; ch < 5; ++ch) {
      s16x8 kf[4];
#pragma unroll
      for (int a = 0; a < 4; ++a)
        kf[a] = *(const s16x8*)(sK + (size_t)(a * 16 + lr) * Dp16 + ch * 32 +
                                lg * 8);
#pragma unroll
      for (int a = 0; a < 4; ++a) {
        s[a][0] = __builtin_amdgcn_mfma_f32_16x16x32_bf16(kf[a], qf[0][ch],
                                                          s[a][0], 0, 0, 0);
        s[a][1] = __builtin_amdgcn_mfma_f32_16x16x32_bf16(kf[a], qf[1][ch],
                                                          s[a][1], 0, 0, 0);
      }
    }

#pragma unroll
    for (int qt = 0; qt < 2; ++qt) {
      float tm = s[0][qt][0];
#pragma unroll
      for (int a = 0; a < 4; ++a)
#pragma unroll
        for (int r = 0; r < 4; ++r) tm = fmaxf(tm, s[a][qt][r]);
      tm = fmaxf(tm, __shfl_xor(tm, 16));
      tm = fmaxf(tm, __shfl_xor(tm, 32));
      const float mo = mreg[qt];
      const float mn = fmaxf(mo, tm);
      float p[4][4];
      float ls = 0.f;
#pragma unroll
      for (int a = 0; a < 4; ++a)
#pragma unroll
        for (int r = 0; r < 4; ++r) {
          p[a][r] = __expf(s[a][qt][r] - mn);
          ls += p[a][r];
        }
      ls += __shfl_xor(ls, 16);
      ls += __shfl_xor(ls, 32);
      const float f = __expf(mo - mn);
      lreg[qt] = lreg[qt] * f + ls;
      mreg[qt] = mn;
#pragma unroll
      for (int a = 0; a < 4; ++a) {
        uint2 u;
        u.x = bfpair(p[a][0], p[a][1]);
        u.y = bfpair(p[a][2], p[a][3]);
        *(uint2*)(sP[w] + (size_t)(qt * 16 + lr) * PSTR + a * 16 + lg * 4) = u;
      }
      if (__any(mn > mo)) {
        float fr[4];
#pragma unroll
        for (int r = 0; r < 4; ++r) fr[r] = __shfl(f, lg * 4 + r, 64);
#pragma unroll
        for (int dt = 0; dt < DT; ++dt)
#pragma unroll
          for (int r = 0; r < 4; ++r) o[qt][dt][r] *= fr[r];
      }
    }

#pragma unroll
    for (int c = 0; c < 2; ++c) {
      const s16x8 pa0 =
          *(const s16x8*)(sP[w] + (size_t)lr * PSTR + c * 32 + lg * 8);
      const s16x8 pa1 =
          *(const s16x8*)(sP[w] + (size_t)(16 + lr) * PSTR + c * 32 + lg * 8);
#pragma unroll
      for (int dt = 0; dt < DT; ++dt) {
        const s16x8 vf = *(const s16x8*)(sVt + (size_t)(dt * 16 + lr) * VSTR +
                                         c * 32 + lg * 8);
        o[0][dt] =
            __builtin_amdgcn_mfma_f32_16x16x32_bf16(pa0, vf, o[0][dt], 0, 0, 0);
        o[1][dt] =
            __builtin_amdgcn_mfma_f32_16x16x32_bf16(pa1, vf, o[1][dt], 0, 0, 0);
      }
    }
  }

#pragma unroll
  for (int qt = 0; qt < 2; ++qt) {
    const float inv = 1.f / lreg[qt];
    float ir[4];
#pragma unroll
    for (int r = 0; r < 4; ++r) ir[r] = __shfl(inv, lg * 4 + r, 64);
#pragma unroll
    for (int dt = 0; dt < DT; ++dt) {
      const int d = dt * 16 + lr;
      if (d < D_) {
#pragma unroll
        for (int r = 0; r < 4; ++r) {
          const int qrow = q0 + w * QW + qt * 16 + lg * 4 + r;
          out[((size_t)b * N_ + qrow) * D_ + d] = o[qt][dt][r] * ir[r];
        }
      }
    }
  }
}

extern "C" void kernel_launch(void* const* d_in, const int* in_sizes, int n_in,
                              void* d_out, int out_size, void* d_ws,
                              size_t ws_size, hipStream_t stream) {
  const float* q = (const float*)d_in[0];
  const float* k = (const float*)d_in[1];
  const float* v = (const float*)d_in[2];
  const float* Wq = (const float*)d_in[3];
  const float* bq = (const float*)d_in[4];
  const float* Wk = (const float*)d_in[5];
  const float* bk = (const float*)d_in[6];
  const float* Wv = (const float*)d_in[7];
  const float* bv = (const float*)d_in[8];
  float* out = (float*)d_out;

  char* wsb = (char*)d_ws;
  ushort* Qb16 = (ushort*)(wsb);
  ushort* Kb16 = (ushort*)(wsb + 5242880);
  ushort* Vt = (ushort*)(wsb + 10485760);
  float* wp = (float*)(wsb + 15728640);

  hipLaunchKernelGGL(pad_w_kernel, dim3(3), dim3(256), 0, stream, Wq, Wk, Wv,
                     wp);
  hipLaunchKernelGGL(proj_kernel, dim3(BN / 64, 3), dim3(256), 0, stream, q, k,
                     v, bq, bk, bv, wp, Qb16, Kb16, Vt);
  hipLaunchKernelGGL(attn_mfma, dim3(N_ / 64, B_), dim3(128), 0, stream, Qb16,
                     Kb16, Vt, out);
}

// Round 3
// 149.106 us; speedup vs baseline: 6.9766x; 1.2028x over previous
//
#include <hip/hip_runtime.h>

#define B_ 8
#define N_ 2048
#define D_ 131
#define DP 132        // fp32 padded dim (proj compute)
#define Dp16 160      // bf16 padded dim (5 chunks of 32)
#define BN (B_ * N_)
#define KB 32         // keys per MFMA tile
#define DT 9          // d-tiles of 16 for PV (144 >= 131)
#define PSTR 40       // sP row stride (ushort)
#define COSTR 145     // combine O row stride (float)
#define TSTR 72       // proj transpose-stage row stride (ushort), 144B = 16B-aligned

typedef __attribute__((ext_vector_type(8))) short s16x8;
typedef __attribute__((ext_vector_type(4))) float f32x4;

__device__ __forceinline__ float dot4f(const float4& a, const float4& b) {
  return a.x * b.x + a.y * b.y + a.z * b.z + a.w * b.w;
}
__device__ __forceinline__ ushort f2bf(float x) {
  uint u = __float_as_uint(x);
  u += 0x7fffu + ((u >> 16) & 1u);
  return (ushort)(u >> 16);
}
__device__ __forceinline__ uint bfpair(float a, float b) {
  uint ua = __float_as_uint(a);
  ua += 0x7fffu + ((ua >> 16) & 1u);
  uint ub = __float_as_uint(b);
  ub += 0x7fffu + ((ub >> 16) & 1u);
  return (ua >> 16) | (ub & 0xffff0000u);
}

// ---------------------------------------------------------------------------
// Kernel 0: pad W rows (131 fp32) to [131][132] fp32. grid(3).
// ---------------------------------------------------------------------------
__global__ void pad_w_kernel(const float* __restrict__ Wq,
                             const float* __restrict__ Wk,
                             const float* __restrict__ Wv,
                             float* __restrict__ wp) {
  const int p = blockIdx.x;
  const float* __restrict__ W = (p == 0) ? Wq : (p == 1) ? Wk : Wv;
  float* __restrict__ o = wp + (size_t)p * D_ * DP;
  for (int i = threadIdx.x; i < D_ * DP; i += blockDim.x) {
    const int e = i / DP;
    const int d = i - e * DP;
    o[i] = (d < D_) ? W[e * D_ + d] : 0.f;
  }
}

// ---------------------------------------------------------------------------
// Kernel 1: projections (fp32 compute). Emits bf16:
//   p=0: Qb16[b][n][160], scaled 1/sqrt(131), zero-padded d>=131
//   p=1: Kb16[b][n][160], zero-padded
//   p=2: Vt  [b][d][2048] transposed via LDS tile (coalesced 128B row writes)
// ---------------------------------------------------------------------------
__global__ __launch_bounds__(256) void proj_kernel(
    const float* __restrict__ q, const float* __restrict__ k,
    const float* __restrict__ v, const float* __restrict__ bq,
    const float* __restrict__ bk, const float* __restrict__ bv,
    const float* __restrict__ wp, ushort* __restrict__ Qb16,
    ushort* __restrict__ Kb16, ushort* __restrict__ Vt) {
  const int p = blockIdx.y;
  const float* __restrict__ x = (p == 0) ? q : (p == 1) ? k : v;
  const float* __restrict__ bias = (p == 0) ? bq : (p == 1) ? bk : bv;
  const float* __restrict__ Wp = wp + (size_t)p * D_ * DP;

  // sX (compute phase) and sT (p==2 output-transpose phase) share storage.
  __shared__ __align__(16) char smem[64 * DP * 4];  // 33792 B
  float(*sX)[DP] = (float(*)[DP])smem;
  ushort(*sT)[TSTR] = (ushort(*)[TSTR])smem;  // [160][72] = 23040 B
  __shared__ float sB[DP];

  const int tid = threadIdx.x;
  const int lane = tid & 63;
  const int wv_ = tid >> 6;
  const int r0 = blockIdx.x * 64;

  for (int r = wv_; r < 64; r += 4) {
    const float* xr = x + (size_t)(r0 + r) * D_;
    for (int d = lane; d < D_; d += 64) sX[r][d] = xr[d];
    if (lane == 0) sX[r][D_] = 0.f;
  }
  if (tid < D_) sB[tid] = bias[tid];
  if (tid == D_) sB[D_] = 0.f;
  __syncthreads();

  const int rg = tid >> 4;
  const int eg = tid & 15;

  float acc[4][9];
#pragma unroll
  for (int i = 0; i < 4; ++i)
#pragma unroll
    for (int j = 0; j < 9; ++j) acc[i][j] = 0.f;

  const float4* sXf = reinterpret_cast<const float4*>(&sX[0][0]);
  const float4* Wf = reinterpret_cast<const float4*>(Wp);

  for (int d4 = 0; d4 < DP / 4; ++d4) {
    float4 xv[4];
#pragma unroll
    for (int i = 0; i < 4; ++i) xv[i] = sXf[(rg + 16 * i) * (DP / 4) + d4];
#pragma unroll
    for (int j = 0; j < 9; ++j) {
      const int e = eg + 16 * j;
      if (e >= D_) continue;
      const float4 wvv = Wf[e * (DP / 4) + d4];
#pragma unroll
      for (int i = 0; i < 4; ++i) acc[i][j] += dot4f(xv[i], wvv);
    }
  }

  const float ISC = 0.08737040566610379f;  // 1/sqrt(131)

  if (p < 2) {
    ushort* arr = (p == 0) ? Qb16 : Kb16;
#pragma unroll
    for (int j = 0; j < 9; ++j) {
      const int e = eg + 16 * j;
      if (e >= D_) continue;
      const float bval = sB[e];
#pragma unroll
      for (int i = 0; i < 4; ++i) {
        const int rn = r0 + rg + 16 * i;
        const float val = acc[i][j] + bval;
        arr[(size_t)rn * Dp16 + e] = f2bf((p == 0) ? val * ISC : val);
      }
    }
    // zero pad cols 131..159
    for (int idx = tid; idx < 64 * 29; idx += 256) {
      const int r = idx / 29;
      const int e = 131 + (idx - r * 29);
      arr[(size_t)(r0 + r) * Dp16 + e] = 0;
    }
  } else {
    // V: transpose through LDS. sX is dead after the acc loop, but other
    // threads may still be reading it -> barrier before aliasing as sT.
    __syncthreads();
    // zero rows 131..159 of sT (incl. pad cols): flat ushort [131*72,160*72)
    {
      uint* z = (uint*)smem;
      for (int idx = tid; idx < (160 - D_) * TSTR / 2; idx += 256)
        z[(D_ * TSTR) / 2 + idx] = 0;
    }
#pragma unroll
    for (int j = 0; j < 9; ++j) {
      const int e = eg + 16 * j;
      if (e >= D_) continue;
      const float bval = sB[e];
#pragma unroll
      for (int i = 0; i < 4; ++i) {
        const int r = rg + 16 * i;
        sT[e][r] = f2bf(acc[i][j] + bval);
      }
    }
    __syncthreads();
    const int bb = r0 >> 11, nn0 = r0 & 2047;
    for (int idx = tid; idx < 160 * 8; idx += 256) {
      const int e = idx >> 3;
      const int c8 = (idx & 7) * 8;
      *(uint4*)(Vt + ((size_t)bb * Dp16 + e) * N_ + nn0 + c8) =
          *(const uint4*)(&sT[e][c8]);
    }
  }
}

// ---------------------------------------------------------------------------
// Kernel 2: MFMA flash attention, barrier-free main loop.
// grid(512): b = id&7 (XCD-pins each batch's K/V slab to one L2),
// q0 = (id>>3)*32. block = 256 thr = 4 waves; ALL waves share the same 32
// queries, wave w owns keys [512w, 512w+512) (16 tiles of 32). K/V fragments
// read directly from global (L2-resident); P round-trips wave-private LDS.
// End: one barrier pair, wave 0 merges the 4 online-softmax partials.
// ---------------------------------------------------------------------------
__global__ __launch_bounds__(256) void attn_mfma(
    const ushort* __restrict__ Qg, const ushort* __restrict__ Kg,
    const ushort* __restrict__ Vtg, float* __restrict__ out) {
  const int id = blockIdx.x;
  const int b = id & 7;
  const int q0 = (id >> 3) * 32;
  const int tid = threadIdx.x;
  const int w = tid >> 6;
  const int l = tid & 63;
  const int lr = l & 15;
  const int lg = l >> 4;

  __shared__ ushort sP[4][32 * PSTR];   // wave-private P tiles
  __shared__ float cm[3][32], cl[3][32];
  __shared__ float cO[3][32][COSTR];

  // Q fragments (all waves: same 32 queries)
  s16x8 qf[2][5];
  {
    const ushort* Qbase = Qg + (size_t)(b * N_ + q0) * Dp16;
#pragma unroll
    for (int qt = 0; qt < 2; ++qt)
#pragma unroll
      for (int ch = 0; ch < 5; ++ch)
        qf[qt][ch] = *(const s16x8*)(Qbase + (size_t)(qt * 16 + lr) * Dp16 +
                                     ch * 32 + lg * 8);
  }

  f32x4 o[2][DT];
#pragma unroll
  for (int qt = 0; qt < 2; ++qt)
#pragma unroll
    for (int dt = 0; dt < DT; ++dt) o[qt][dt] = (f32x4){0.f, 0.f, 0.f, 0.f};

  float mreg[2] = {-1e30f, -1e30f};
  float lreg[2] = {0.f, 0.f};

  const ushort* Kb = Kg + (size_t)b * N_ * Dp16;
  const ushort* Vb = Vtg + (size_t)b * Dp16 * N_;

  for (int kt = w * 16; kt < w * 16 + 16; ++kt) {
    const ushort* Krow = Kb + (size_t)kt * KB * Dp16;

    // ---- S^T = K * Q^T ----
    f32x4 s[2][2];
#pragma unroll
    for (int a = 0; a < 2; ++a)
#pragma unroll
      for (int qt = 0; qt < 2; ++qt) s[a][qt] = (f32x4){0.f, 0.f, 0.f, 0.f};
#pragma unroll
    for (int ch = 0; ch < 5; ++ch) {
      s16x8 kf[2];
#pragma unroll
      for (int a = 0; a < 2; ++a)
        kf[a] = *(const s16x8*)(Krow + (size_t)(a * 16 + lr) * Dp16 + ch * 32 +
                                lg * 8);
#pragma unroll
      for (int a = 0; a < 2; ++a) {
        s[a][0] = __builtin_amdgcn_mfma_f32_16x16x32_bf16(kf[a], qf[0][ch],
                                                          s[a][0], 0, 0, 0);
        s[a][1] = __builtin_amdgcn_mfma_f32_16x16x32_bf16(kf[a], qf[1][ch],
                                                          s[a][1], 0, 0, 0);
      }
    }

    // ---- hoist V loads: overlap global latency with softmax VALU ----
    s16x8 vf[DT];
#pragma unroll
    for (int dt = 0; dt < DT; ++dt)
      vf[dt] = *(const s16x8*)(Vb + (size_t)(dt * 16 + lr) * N_ + kt * KB +
                               lg * 8);

    // ---- online softmax (query = lane&15, replicated over lane groups) ----
#pragma unroll
    for (int qt = 0; qt < 2; ++qt) {
      float tm = s[0][qt][0];
#pragma unroll
      for (int a = 0; a < 2; ++a)
#pragma unroll
        for (int r = 0; r < 4; ++r) tm = fmaxf(tm, s[a][qt][r]);
      tm = fmaxf(tm, __shfl_xor(tm, 16));
      tm = fmaxf(tm, __shfl_xor(tm, 32));
      const float mo = mreg[qt];
      const float mn = fmaxf(mo, tm);
      float pr[2][4];
      float ls = 0.f;
#pragma unroll
      for (int a = 0; a < 2; ++a)
#pragma unroll
        for (int r = 0; r < 4; ++r) {
          pr[a][r] = __expf(s[a][qt][r] - mn);
          ls += pr[a][r];
        }
      ls += __shfl_xor(ls, 16);
      ls += __shfl_xor(ls, 32);
      const float f = __expf(mo - mn);
      lreg[qt] = lreg[qt] * f + ls;
      mreg[qt] = mn;
#pragma unroll
      for (int a = 0; a < 2; ++a) {
        uint2 u;
        u.x = bfpair(pr[a][0], pr[a][1]);
        u.y = bfpair(pr[a][2], pr[a][3]);
        *(uint2*)(sP[w] + (size_t)(qt * 16 + lr) * PSTR + a * 16 + lg * 4) = u;
      }
      if (__any(mn > mo)) {
        float fr[4];
#pragma unroll
        for (int r = 0; r < 4; ++r) fr[r] = __shfl(f, lg * 4 + r, 64);
#pragma unroll
        for (int dt = 0; dt < DT; ++dt)
#pragma unroll
          for (int r = 0; r < 4; ++r) o[qt][dt][r] *= fr[r];
      }
    }

    // ---- PV ----
    const s16x8 pa0 = *(const s16x8*)(sP[w] + (size_t)lr * PSTR + lg * 8);
    const s16x8 pa1 =
        *(const s16x8*)(sP[w] + (size_t)(16 + lr) * PSTR + lg * 8);
#pragma unroll
    for (int dt = 0; dt < DT; ++dt) {
      o[0][dt] =
          __builtin_amdgcn_mfma_f32_16x16x32_bf16(pa0, vf[dt], o[0][dt], 0, 0, 0);
      o[1][dt] =
          __builtin_amdgcn_mfma_f32_16x16x32_bf16(pa1, vf[dt], o[1][dt], 0, 0, 0);
    }
  }

  // ---- cross-wave merge of (m, l, O) partials ----
  __syncthreads();
  if (w > 0) {
    if (lg == 0) {
      cm[w - 1][lr] = mreg[0];
      cm[w - 1][16 + lr] = mreg[1];
      cl[w - 1][lr] = lreg[0];
      cl[w - 1][16 + lr] = lreg[1];
    }
#pragma unroll
    for (int qt = 0; qt < 2; ++qt)
#pragma unroll
      for (int dt = 0; dt < DT; ++dt)
#pragma unroll
        for (int r = 0; r < 4; ++r)
          cO[w - 1][qt * 16 + lg * 4 + r][dt * 16 + lr] = o[qt][dt][r];
  }
  __syncthreads();
  if (w == 0) {
#pragma unroll
    for (int qt = 0; qt < 2; ++qt) {
      const int qq = qt * 16 + lr;
      const float m1 = cm[0][qq], m2 = cm[1][qq], m3 = cm[2][qq];
      float M = fmaxf(fmaxf(mreg[qt], m1), fmaxf(m2, m3));
      const float e0 = __expf(mreg[qt] - M);
      const float e1 = __expf(m1 - M);
      const float e2 = __expf(m2 - M);
      const float e3 = __expf(m3 - M);
      const float L =
          lreg[qt] * e0 + cl[0][qq] * e1 + cl[1][qq] * e2 + cl[2][qq] * e3;
      const float inv = 1.f / L;
      float er0[4], er1[4], er2[4], er3[4], ir[4];
#pragma unroll
      for (int r = 0; r < 4; ++r) {
        er0[r] = __shfl(e0, lg * 4 + r, 64);
        er1[r] = __shfl(e1, lg * 4 + r, 64);
        er2[r] = __shfl(e2, lg * 4 + r, 64);
        er3[r] = __shfl(e3, lg * 4 + r, 64);
        ir[r] = __shfl(inv, lg * 4 + r, 64);
      }
#pragma unroll
      for (int dt = 0; dt < DT; ++dt) {
        const int d = dt * 16 + lr;
        if (d < D_) {
#pragma unroll
          for (int r = 0; r < 4; ++r) {
            const int row = qt * 16 + lg * 4 + r;
            const float val = o[qt][dt][r] * er0[r] + cO[0][row][d] * er1[r] +
                              cO[1][row][d] * er2[r] + cO[2][row][d] * er3[r];
            out[((size_t)b * N_ + q0 + row) * D_ + d] = val * ir[r];
          }
        }
      }
    }
  }
}

extern "C" void kernel_launch(void* const* d_in, const int* in_sizes, int n_in,
                              void* d_out, int out_size, void* d_ws,
                              size_t ws_size, hipStream_t stream) {
  const float* q = (const float*)d_in[0];
  const float* k = (const float*)d_in[1];
  const float* v = (const float*)d_in[2];
  const float* Wq = (const float*)d_in[3];
  const float* bq = (const float*)d_in[4];
  const float* Wk = (const float*)d_in[5];
  const float* bk = (const float*)d_in[6];
  const float* Wv = (const float*)d_in[7];
  const float* bv = (const float*)d_in[8];
  float* out = (float*)d_out;

  char* wsb = (char*)d_ws;
  ushort* Qb16 = (ushort*)(wsb);
  ushort* Kb16 = (ushort*)(wsb + 5242880);
  ushort* Vt = (ushort*)(wsb + 10485760);
  float* wp = (float*)(wsb + 15728640);

  hipLaunchKernelGGL(pad_w_kernel, dim3(3), dim3(256), 0, stream, Wq, Wk, Wv,
                     wp);
  hipLaunchKernelGGL(proj_kernel, dim3(BN / 64, 3), dim3(256), 0, stream, q, k,
                     v, bq, bk, bv, wp, Qb16, Kb16, Vt);
  hipLaunchKernelGGL(attn_mfma, dim3(512), dim3(256), 0, stream, Qb16, Kb16,
                     Vt, out);
}

// Round 4
// 130.671 us; speedup vs baseline: 7.9609x; 1.1411x over previous
//
#include <hip/hip_runtime.h>

#define B_ 8
#define N_ 2048
#define D_ 131
#define Dp16 160      // bf16 padded dim (5 chunks of 32)
#define BN (B_ * N_)
#define KB 32         // keys per MFMA tile
#define DT 9          // d-tiles of 16 for PV (144 >= 131; col 131 = ones for l)
#define VROWS 144
#define PSTR 40       // sP row stride (ushort)
#define COSTR 145     // combine O row stride (float)
#define TSTR 136      // proj V-transpose stage row stride (ushort), 272B

typedef __attribute__((ext_vector_type(8))) short s16x8;
typedef __attribute__((ext_vector_type(4))) float f32x4;

__device__ __forceinline__ ushort f2bf(float x) {
  uint u = __float_as_uint(x);
  u += 0x7fffu + ((u >> 16) & 1u);
  return (ushort)(u >> 16);
}
__device__ __forceinline__ float bf2f(ushort h) {
  return __uint_as_float(((uint)h) << 16);
}
__device__ __forceinline__ uint bfpair(float a, float b) {
  uint ua = __float_as_uint(a);
  ua += 0x7fffu + ((ua >> 16) & 1u);
  uint ub = __float_as_uint(b);
  ub += 0x7fffu + ((ub >> 16) & 1u);
  return (ua >> 16) | (ub & 0xffff0000u);
}

// ---------------------------------------------------------------------------
// Kernel 0: cast W -> hi/lo bf16, padded [144][160], rows/cols >=131 zero.
// Whl layout: [p][2][144][160] ushort. grid(3), block(256).
// ---------------------------------------------------------------------------
__global__ void cast_w_kernel(const float* __restrict__ Wq,
                              const float* __restrict__ Wk,
                              const float* __restrict__ Wv,
                              ushort* __restrict__ Whl) {
  const int p = blockIdx.x;
  const float* __restrict__ W = (p == 0) ? Wq : (p == 1) ? Wk : Wv;
  ushort* __restrict__ H = Whl + (size_t)p * 2 * 144 * Dp16;
  ushort* __restrict__ L = H + 144 * Dp16;
  for (int i = threadIdx.x; i < 144 * Dp16; i += blockDim.x) {
    const int e = i / Dp16;
    const int d = i - e * Dp16;
    const float val = (e < D_ && d < D_) ? W[e * D_ + d] : 0.f;
    const ushort h = f2bf(val);
    H[i] = h;
    L[i] = f2bf(val - bf2f(h));
  }
}

// ---------------------------------------------------------------------------
// Kernel 1: MFMA projections, 3-pass bf16 hi/lo (fp32-grade accuracy).
// grid(128, 3), block(256) = 4 waves; wave w owns rows m0..m0+31 (2 m-tiles).
// Emits: p=0 Qb16[rn][160] (* 1/sqrt(131)); p=1 Kb16[rn][160];
//        p=2 Vt[b][144][2048] transposed, row131=ones, rows132..143=0.
// ---------------------------------------------------------------------------
__global__ __launch_bounds__(256) void proj_gemm(
    const float* __restrict__ q, const float* __restrict__ k,
    const float* __restrict__ v, const float* __restrict__ bq,
    const float* __restrict__ bk, const float* __restrict__ bv,
    const ushort* __restrict__ Whl, ushort* __restrict__ Qb16,
    ushort* __restrict__ Kb16, ushort* __restrict__ Vt) {
  const int p = blockIdx.y;
  const float* __restrict__ x = (p == 0) ? q : (p == 1) ? k : v;
  const float* __restrict__ bias = (p == 0) ? bq : (p == 1) ? bk : bv;
  const ushort* __restrict__ Wh = Whl + (size_t)p * 2 * 144 * Dp16;
  const ushort* __restrict__ Wl = Wh + 144 * Dp16;

  __shared__ ushort sC[128 * Dp16];  // 40960 B; reused as sT[144][TSTR] for p==2
  __shared__ float sB[Dp16];

  const int tid = threadIdx.x;
  const int w = tid >> 6;
  const int l = tid & 63;
  const int lr = l & 15;
  const int lg = l >> 4;
  const int rn0 = blockIdx.x * 128;
  const int m0 = rn0 + w * 32;

  if (tid < Dp16) sB[tid] = (tid < D_) ? bias[tid] : 0.f;
  __syncthreads();

  f32x4 acc[2][9];
#pragma unroll
  for (int a = 0; a < 2; ++a)
#pragma unroll
    for (int et = 0; et < 9; ++et) acc[a][et] = (f32x4){0.f, 0.f, 0.f, 0.f};

#pragma unroll
  for (int ch = 0; ch < 5; ++ch) {
    s16x8 ah[2], al[2];
#pragma unroll
    for (int a = 0; a < 2; ++a) {
      const float* xr = x + (size_t)(m0 + a * 16 + lr) * D_;
#pragma unroll
      for (int j = 0; j < 8; ++j) {
        const int col = ch * 32 + lg * 8 + j;
        const float xv = (col < D_) ? xr[col] : 0.f;
        const ushort h = f2bf(xv);
        ah[a][j] = (short)h;
        al[a][j] = (short)f2bf(xv - bf2f(h));
      }
    }
#pragma unroll
    for (int et = 0; et < 9; ++et) {
      const s16x8 bh =
          *(const s16x8*)(Wh + (size_t)(et * 16 + lr) * Dp16 + ch * 32 + lg * 8);
      const s16x8 bl =
          *(const s16x8*)(Wl + (size_t)(et * 16 + lr) * Dp16 + ch * 32 + lg * 8);
#pragma unroll
      for (int a = 0; a < 2; ++a) {
        acc[a][et] =
            __builtin_amdgcn_mfma_f32_16x16x32_bf16(ah[a], bh, acc[a][et], 0, 0, 0);
        acc[a][et] =
            __builtin_amdgcn_mfma_f32_16x16x32_bf16(al[a], bh, acc[a][et], 0, 0, 0);
        acc[a][et] =
            __builtin_amdgcn_mfma_f32_16x16x32_bf16(ah[a], bl, acc[a][et], 0, 0, 0);
      }
    }
  }

  const float ISC = 0.08737040566610379f;  // 1/sqrt(131)

  if (p < 2) {
    // C rows -> sC[m_local][e] bf16 (e 0..143; 131..143 are exact zeros)
#pragma unroll
    for (int et = 0; et < 9; ++et) {
      const int e = et * 16 + lr;
      const float bval = sB[e];
#pragma unroll
      for (int a = 0; a < 2; ++a) {
        const int ml = w * 32 + a * 16 + lg * 4;
#pragma unroll
        for (int r = 0; r < 4; ++r) {
          float val = acc[a][et][r] + bval;
          if (p == 0) val *= ISC;
          sC[(size_t)(ml + r) * Dp16 + e] = f2bf(val);
        }
      }
    }
    // zero cols 144..159
    for (int i = tid; i < 128 * 8; i += 256) {
      const int row = i >> 3;
      ((uint*)sC)[row * (Dp16 / 2) + 72 + (i & 7)] = 0;
    }
    __syncthreads();
    ushort* __restrict__ arr = (p == 0) ? Qb16 : Kb16;
    uint4* dst = (uint4*)(arr + (size_t)rn0 * Dp16);
    const uint4* src = (const uint4*)sC;
    for (int i = tid; i < 128 * Dp16 * 2 / 16; i += 256) dst[i] = src[i];
  } else {
    // V: transpose-stage sT[e][m_local]
    ushort* sT = sC;
#pragma unroll
    for (int et = 0; et < 9; ++et) {
      const int e = et * 16 + lr;
      if (e < D_) {
        const float bval = sB[e];
#pragma unroll
        for (int a = 0; a < 2; ++a) {
          const int ml = w * 32 + a * 16 + lg * 4;
#pragma unroll
          for (int r = 0; r < 4; ++r)
            sT[(size_t)e * TSTR + ml + r] = f2bf(acc[a][et][r] + bval);
        }
      }
    }
    // rows 131..143: 131 = ones (for l-fusion), rest 0
    for (int i = tid; i < 13 * 128; i += 256) {
      const int e = D_ + (i >> 7);
      const int m = i & 127;
      sT[(size_t)e * TSTR + m] = (e == D_) ? (ushort)0x3F80 : (ushort)0;
    }
    __syncthreads();
    const int bb = rn0 >> 11, n0 = rn0 & 2047;
    for (int i = tid; i < VROWS * 16; i += 256) {
      const int e = i >> 4;
      const int c8 = (i & 15) * 8;
      *(uint4*)(Vt + ((size_t)bb * VROWS + e) * N_ + n0 + c8) =
          *(const uint4*)(sT + (size_t)e * TSTR + c8);
    }
  }
}

// ---------------------------------------------------------------------------
// Kernel 2: MFMA flash attention. grid(512): b=id&7, q0=(id>>3)*32.
// block 256 = 4 waves sharing the same 32 queries (Q in LDS); wave w owns
// keys [512w, 512w+512) as 16 tiles of 32. K double-buffered in registers
// (prefetch next tile before softmax); V loaded at tile start, used at PV.
// l is fused into PV via Vt's ones-row (d=131). Defer-max skips rescale.
// End: single barrier, wave 0 merges 4 partials (m, O[incl. l col]).
// ---------------------------------------------------------------------------
__global__ __launch_bounds__(256, 2) void attn_mfma(
    const ushort* __restrict__ Qg, const ushort* __restrict__ Kg,
    const ushort* __restrict__ Vtg, float* __restrict__ out) {
  const int id = blockIdx.x;
  const int b = id & 7;
  const int q0 = (id >> 3) * 32;
  const int tid = threadIdx.x;
  const int w = tid >> 6;
  const int l = tid & 63;
  const int lr = l & 15;
  const int lg = l >> 4;

  __shared__ ushort sQ[32 * Dp16];     // 10240 B, shared by all waves
  __shared__ ushort sP[4][32 * PSTR];  // wave-private P tiles
  __shared__ float cm[3][32];
  __shared__ float cO[3][32][COSTR];   // 55680 B

  const ushort* Kb = Kg + (size_t)b * N_ * Dp16;
  const ushort* Vb = Vtg + (size_t)b * VROWS * N_;
  ushort* sPw = sP[w];

  // prefetch first K tile (no LDS dependency -> before barrier)
  s16x8 kA[2][5], kB[2][5];
  {
    const ushort* Kr = Kb + (size_t)(w * 16) * KB * Dp16;
#pragma unroll
    for (int ch = 0; ch < 5; ++ch)
#pragma unroll
      for (int a = 0; a < 2; ++a)
        kA[a][ch] =
            *(const s16x8*)(Kr + (size_t)(a * 16 + lr) * Dp16 + ch * 32 + lg * 8);
  }

  // stage Q (32 rows x 160)
  {
    const uint4* src = (const uint4*)(Qg + (size_t)(b * N_ + q0) * Dp16);
    uint4* dst = (uint4*)sQ;
    for (int i = tid; i < 32 * Dp16 * 2 / 16; i += 256) dst[i] = src[i];
  }
  __syncthreads();

  f32x4 o[2][DT];
#pragma unroll
  for (int qt = 0; qt < 2; ++qt)
#pragma unroll
    for (int dt = 0; dt < DT; ++dt) o[qt][dt] = (f32x4){0.f, 0.f, 0.f, 0.f};
  float mreg[2] = {-1e30f, -1e30f};

  auto tile_body = [&](s16x8(&KC)[2][5], s16x8(&KN)[2][5], int kt, int ktn) {
    // V loads for this tile (consumed at PV, ~1k cycles later)
    s16x8 vf[DT];
#pragma unroll
    for (int dt = 0; dt < DT; ++dt)
      vf[dt] =
          *(const s16x8*)(Vb + (size_t)(dt * 16 + lr) * N_ + kt * KB + lg * 8);
    // prefetch next K tile
    {
      const ushort* Kr = Kb + (size_t)ktn * KB * Dp16;
#pragma unroll
      for (int ch = 0; ch < 5; ++ch)
#pragma unroll
        for (int a = 0; a < 2; ++a)
          KN[a][ch] = *(const s16x8*)(Kr + (size_t)(a * 16 + lr) * Dp16 +
                                      ch * 32 + lg * 8);
    }
    // S^T = K * Q^T  (col of C = query = lane&15)
    f32x4 s[2][2];
#pragma unroll
    for (int a = 0; a < 2; ++a)
#pragma unroll
      for (int qt = 0; qt < 2; ++qt) s[a][qt] = (f32x4){0.f, 0.f, 0.f, 0.f};
#pragma unroll
    for (int ch = 0; ch < 5; ++ch) {
      const s16x8 qf0 = *(const s16x8*)(sQ + (size_t)lr * Dp16 + ch * 32 + lg * 8);
      const s16x8 qf1 =
          *(const s16x8*)(sQ + (size_t)(16 + lr) * Dp16 + ch * 32 + lg * 8);
      s[0][0] = __builtin_amdgcn_mfma_f32_16x16x32_bf16(KC[0][ch], qf0, s[0][0], 0, 0, 0);
      s[1][0] = __builtin_amdgcn_mfma_f32_16x16x32_bf16(KC[1][ch], qf0, s[1][0], 0, 0, 0);
      s[0][1] = __builtin_amdgcn_mfma_f32_16x16x32_bf16(KC[0][ch], qf1, s[0][1], 0, 0, 0);
      s[1][1] = __builtin_amdgcn_mfma_f32_16x16x32_bf16(KC[1][ch], qf1, s[1][1], 0, 0, 0);
    }
    // online softmax, defer-max; l-sum is fused into PV via ones-row
#pragma unroll
    for (int qt = 0; qt < 2; ++qt) {
      float tm = s[0][qt][0];
#pragma unroll
      for (int a = 0; a < 2; ++a)
#pragma unroll
        for (int r = 0; r < 4; ++r) tm = fmaxf(tm, s[a][qt][r]);
      tm = fmaxf(tm, __shfl_xor(tm, 16, 64));
      tm = fmaxf(tm, __shfl_xor(tm, 32, 64));
      if (__any(tm > mreg[qt])) {
        const float mo = mreg[qt];
        const float mn = fmaxf(mo, tm);
        mreg[qt] = mn;
        const float f = __expf(mo - mn);
        float fr[4];
#pragma unroll
        for (int r = 0; r < 4; ++r) fr[r] = __shfl(f, lg * 4 + r, 64);
#pragma unroll
        for (int dt = 0; dt < DT; ++dt)
#pragma unroll
          for (int r = 0; r < 4; ++r) o[qt][dt][r] *= fr[r];
      }
      const float mcur = mreg[qt];
#pragma unroll
      for (int a = 0; a < 2; ++a) {
        const float p0 = __expf(s[a][qt][0] - mcur);
        const float p1 = __expf(s[a][qt][1] - mcur);
        const float p2 = __expf(s[a][qt][2] - mcur);
        const float p3 = __expf(s[a][qt][3] - mcur);
        uint2 u;
        u.x = bfpair(p0, p1);
        u.y = bfpair(p2, p3);
        *(uint2*)(sPw + (size_t)(qt * 16 + lr) * PSTR + a * 16 + lg * 4) = u;
      }
    }
    // PV (+ fused l in dt=8 col 131)
    const s16x8 pa0 = *(const s16x8*)(sPw + (size_t)lr * PSTR + lg * 8);
    const s16x8 pa1 = *(const s16x8*)(sPw + (size_t)(16 + lr) * PSTR + lg * 8);
#pragma unroll
    for (int dt = 0; dt < DT; ++dt) {
      o[0][dt] = __builtin_amdgcn_mfma_f32_16x16x32_bf16(pa0, vf[dt], o[0][dt], 0, 0, 0);
      o[1][dt] = __builtin_amdgcn_mfma_f32_16x16x32_bf16(pa1, vf[dt], o[1][dt], 0, 0, 0);
    }
  };

  for (int i = 0; i < 8; ++i) {
    const int kt = w * 16 + 2 * i;
    tile_body(kA, kB, kt, kt + 1);
    tile_body(kB, kA, kt + 1, (i < 7) ? kt + 2 : kt + 1);
  }

  // ---- cross-wave merge ----
  if (w > 0) {
    if (lg == 0) {
      cm[w - 1][lr] = mreg[0];
      cm[w - 1][16 + lr] = mreg[1];
    }
#pragma unroll
    for (int qt = 0; qt < 2; ++qt)
#pragma unroll
      for (int dt = 0; dt < DT; ++dt)
#pragma unroll
        for (int r = 0; r < 4; ++r)
          cO[w - 1][qt * 16 + lg * 4 + r][dt * 16 + lr] = o[qt][dt][r];
  }
  __syncthreads();
  if (w == 0) {
#pragma unroll
    for (int qt = 0; qt < 2; ++qt) {
      const int qq = qt * 16 + lr;
      const float m1 = cm[0][qq], m2 = cm[1][qq], m3 = cm[2][qq];
      const float M = fmaxf(fmaxf(mreg[qt], m1), fmaxf(m2, m3));
      const float e0 = __expf(mreg[qt] - M);
      const float e1 = __expf(m1 - M);
      const float e2 = __expf(m2 - M);
      const float e3 = __expf(m3 - M);
      float er0[4], er1[4], er2[4], er3[4];
#pragma unroll
      for (int r = 0; r < 4; ++r) {
        er0[r] = __shfl(e0, lg * 4 + r, 64);
        er1[r] = __shfl(e1, lg * 4 + r, 64);
        er2[r] = __shfl(e2, lg * 4 + r, 64);
        er3[r] = __shfl(e3, lg * 4 + r, 64);
      }
      // L first (dt=8, col d=131 <-> lr==3)
      float l8[4];
#pragma unroll
      for (int r = 0; r < 4; ++r) {
        const int row = qt * 16 + lg * 4 + r;
        l8[r] = o[qt][8][r] * er0[r] + cO[0][row][128 + lr] * er1[r] +
                cO[1][row][128 + lr] * er2[r] + cO[2][row][128 + lr] * er3[r];
      }
      float ir[4];
#pragma unroll
      for (int r = 0; r < 4; ++r)
        ir[r] = 1.f / __shfl(l8[r], (l & 48) + 3, 64);
#pragma unroll
      for (int dt = 0; dt < DT; ++dt) {
        const int d = dt * 16 + lr;
        if (d < D_) {
#pragma unroll
          for (int r = 0; r < 4; ++r) {
            const int row = qt * 16 + lg * 4 + r;
            const float val = (dt == 8 ? l8[r]
                                       : o[qt][dt][r] * er0[r] +
                                             cO[0][row][d] * er1[r] +
                                             cO[1][row][d] * er2[r] +
                                             cO[2][row][d] * er3[r]);
            out[((size_t)b * N_ + q0 + row) * D_ + d] = val * ir[r];
          }
        }
      }
    }
  }
}

extern "C" void kernel_launch(void* const* d_in, const int* in_sizes, int n_in,
                              void* d_out, int out_size, void* d_ws,
                              size_t ws_size, hipStream_t stream) {
  const float* q = (const float*)d_in[0];
  const float* k = (const float*)d_in[1];
  const float* v = (const float*)d_in[2];
  const float* Wq = (const float*)d_in[3];
  const float* bq = (const float*)d_in[4];
  const float* Wk = (const float*)d_in[5];
  const float* bk = (const float*)d_in[6];
  const float* Wv = (const float*)d_in[7];
  const float* bv = (const float*)d_in[8];
  float* out = (float*)d_out;

  // ws layout (bytes):
  //   Qb16 [16384][160]u16 @ 0          (5,242,880)
  //   Kb16 [16384][160]u16 @ 5,242,880  (5,242,880)
  //   Vt   [8][144][2048]u16 @ 10,485,760 (4,718,592)
  //   Whl  [3][2][144][160]u16 @ 15,204,352 (276,480)
  char* wsb = (char*)d_ws;
  ushort* Qb16 = (ushort*)(wsb);
  ushort* Kb16 = (ushort*)(wsb + 5242880);
  ushort* Vt = (ushort*)(wsb + 10485760);
  ushort* Whl = (ushort*)(wsb + 15204352);

  hipLaunchKernelGGL(cast_w_kernel, dim3(3), dim3(256), 0, stream, Wq, Wk, Wv,
                     Whl);
  hipLaunchKernelGGL(proj_gemm, dim3(128, 3), dim3(256), 0, stream, q, k, v,
                     bq, bk, bv, Whl, Qb16, Kb16, Vt);
  hipLaunchKernelGGL(attn_mfma, dim3(512), dim3(256), 0, stream, Qb16, Kb16,
                     Vt, out);
}

// Round 5
// 81.392 us; speedup vs baseline: 12.7808x; 1.6055x over previous
//
#include <hip/hip_runtime.h>

#define B_ 8
#define N_ 2048
#define D_ 131
#define BN (B_ * N_)
#define KB 32         // keys per MFMA tile
#define DT 9          // d-tiles of 16 (144 >= 131; col 131 = ones for l-fusion)
#define PSTR 40       // sP row stride (ushort)
#define COSTR 145     // combine O row stride (float)
#define SXSTR 164     // proj sX row stride (float): 2-way-bank-free frag reads
#define CSTR 168      // proj sC row stride (ushort)
#define TSTR 72       // proj sT row stride (ushort)

typedef __attribute__((ext_vector_type(8))) short s16x8;
typedef __attribute__((ext_vector_type(4))) float f32x4;

__device__ __forceinline__ ushort f2bf(float x) {
  uint u = __float_as_uint(x);
  u += 0x7fffu + ((u >> 16) & 1u);
  return (ushort)(u >> 16);
}
__device__ __forceinline__ float bf2f(ushort h) {
  return __uint_as_float(((uint)h) << 16);
}
__device__ __forceinline__ uint bfpair(float a, float b) {
  uint ua = __float_as_uint(a);
  ua += 0x7fffu + ((ua >> 16) & 1u);
  uint ub = __float_as_uint(b);
  ub += 0x7fffu + ((ub >> 16) & 1u);
  return (ua >> 16) | (ub & 0xffff0000u);
}

// Fragment layouts (all loads in hot loops are 16B/lane, wave-contiguous):
//  Rf (Q or K): [nt(=token/16, global over b)][ch(5)][lane(64)][8]
//  Vf:          [ktg(=key/32, global over b)][dt(9)][lane(64)][8]
//  Whl:         [p(3)][hi/lo(2)][et(9)][ch(5)][lane(64)][8]
__device__ __forceinline__ size_t rf_idx(int nt, int ch, int l) {
  return (((size_t)nt * 5 + ch) * 64 + l) * 8;
}
__device__ __forceinline__ size_t vf_idx(int ktg, int dt, int l) {
  return (((size_t)ktg * 9 + dt) * 64 + l) * 8;
}
__device__ __forceinline__ size_t wf_idx(int p, int h, int et, int ch, int l) {
  return (((((size_t)p * 2 + h) * 9 + et) * 5 + ch) * 64 + l) * 8;
}

// ---------------------------------------------------------------------------
// Kernel 0: W -> hi/lo bf16 fragments. Whl[p][h][et][ch][l][8]. grid(3).
// Fragment value = W[e=et*16+(l&15)][d=ch*32+(l>>4)*8+j], 0 outside 131x131.
// ---------------------------------------------------------------------------
__global__ void cast_w_kernel(const float* __restrict__ Wq,
                              const float* __restrict__ Wk,
                              const float* __restrict__ Wv,
                              ushort* __restrict__ Whl) {
  const int p = blockIdx.x;
  const float* __restrict__ W = (p == 0) ? Wq : (p == 1) ? Wk : Wv;
  for (int i = threadIdx.x; i < 9 * 5 * 64; i += blockDim.x) {
    const int et = i / 320;
    const int rem = i - et * 320;
    const int ch = rem >> 6;
    const int l = rem & 63;
    const int lr = l & 15, lg = l >> 4;
    const int e = et * 16 + lr;
    s16x8 hi, lo;
#pragma unroll
    for (int j = 0; j < 8; ++j) {
      const int d = ch * 32 + lg * 8 + j;
      const float val = (e < D_ && d < D_) ? W[e * D_ + d] : 0.f;
      const ushort h = f2bf(val);
      hi[j] = (short)h;
      lo[j] = (short)f2bf(val - bf2f(h));
    }
    *(s16x8*)(Whl + wf_idx(p, 0, et, ch, l)) = hi;
    *(s16x8*)(Whl + wf_idx(p, 1, et, ch, l)) = lo;
  }
}

// ---------------------------------------------------------------------------
// Kernel 1: MFMA projections, 3-pass bf16 hi/lo. grid(256,3), block 256 =
// 4 waves; 64 tokens/block, wave w owns token-tile w (16 rows).
// x staged in LDS coalesced; W read as coalesced fragments. Epilogue stages
// through LDS and emits fragment layouts (Qf scaled by 1/sqrt(131);
// Vf transposed with ones-row at d=131).
// ---------------------------------------------------------------------------
__global__ __launch_bounds__(256, 3) void proj_gemm(
    const float* __restrict__ q, const float* __restrict__ k,
    const float* __restrict__ v, const float* __restrict__ bq,
    const float* __restrict__ bk, const float* __restrict__ bv,
    const ushort* __restrict__ Whl, ushort* __restrict__ Qf,
    ushort* __restrict__ Kf, ushort* __restrict__ Vf) {
  const int p = blockIdx.y;
  const float* __restrict__ x = (p == 0) ? q : (p == 1) ? k : v;
  const float* __restrict__ bias = (p == 0) ? bq : (p == 1) ? bk : bv;

  __shared__ __align__(16) char smem[64 * SXSTR * 4];  // 41984 B (union)
  float* sX = (float*)smem;    // [64][SXSTR] fp32
  ushort* sC = (ushort*)smem;  // [64][CSTR]  bf16 (p<2 epilogue)
  ushort* sT = (ushort*)smem;  // [144][TSTR] bf16 (p==2 epilogue)
  __shared__ float sB[160];

  const int tid = threadIdx.x;
  const int r0 = blockIdx.x * 64;

  for (int i = tid; i < 64 * SXSTR; i += 256) {
    const int r = i / SXSTR;
    const int d = i - r * SXSTR;
    sX[i] = (d < D_) ? x[(size_t)(r0 + r) * D_ + d] : 0.f;
  }
  if (tid < 160) sB[tid] = (tid < D_) ? bias[tid] : 0.f;
  __syncthreads();

  const int w = tid >> 6;
  const int l = tid & 63;
  const int lr = l & 15;
  const int lg = l >> 4;

  f32x4 acc[9];
#pragma unroll
  for (int et = 0; et < 9; ++et) acc[et] = (f32x4){0.f, 0.f, 0.f, 0.f};

#pragma unroll
  for (int ch = 0; ch < 5; ++ch) {
    const float* xp = sX + (size_t)(w * 16 + lr) * SXSTR + ch * 32 + lg * 8;
    const float4 x0 = *(const float4*)xp;
    const float4 x1 = *(const float4*)(xp + 4);
    const float xv[8] = {x0.x, x0.y, x0.z, x0.w, x1.x, x1.y, x1.z, x1.w};
    s16x8 ah, al;
#pragma unroll
    for (int j = 0; j < 8; ++j) {
      const ushort h = f2bf(xv[j]);
      ah[j] = (short)h;
      al[j] = (short)f2bf(xv[j] - bf2f(h));
    }
#pragma unroll
    for (int et = 0; et < 9; ++et) {
      const s16x8 bh = *(const s16x8*)(Whl + wf_idx(p, 0, et, ch, l));
      const s16x8 bl = *(const s16x8*)(Whl + wf_idx(p, 1, et, ch, l));
      acc[et] = __builtin_amdgcn_mfma_f32_16x16x32_bf16(ah, bh, acc[et], 0, 0, 0);
      acc[et] = __builtin_amdgcn_mfma_f32_16x16x32_bf16(al, bh, acc[et], 0, 0, 0);
      acc[et] = __builtin_amdgcn_mfma_f32_16x16x32_bf16(ah, bl, acc[et], 0, 0, 0);
    }
  }

  const float ISC = 0.08737040566610379f;  // 1/sqrt(131)
  __syncthreads();  // done reading sX

  if (p < 2) {
    // C[m=w*16+lg*4+r][e=et*16+lr] -> sC[m][e]
#pragma unroll
    for (int et = 0; et < 9; ++et) {
      const int e = et * 16 + lr;
      const float bval = sB[e];
#pragma unroll
      for (int r = 0; r < 4; ++r) {
        float val = acc[et][r] + bval;
        if (p == 0) val *= ISC;
        sC[(size_t)(w * 16 + lg * 4 + r) * CSTR + e] = f2bf(val);
      }
    }
    for (int i = tid; i < 64 * 16; i += 256)
      sC[(size_t)(i >> 4) * CSTR + 144 + (i & 15)] = 0;
    __syncthreads();
    ushort* __restrict__ dst = (p == 0) ? Qf : Kf;
    const int nt0 = r0 >> 4;
    for (int i = tid; i < 4 * 5 * 64; i += 256) {
      const int nt = i / 320;
      const int rem = i - nt * 320;
      const int ch = rem >> 6;
      const int l2 = rem & 63;
      const s16x8 fr = *(const s16x8*)(sC + (size_t)(nt * 16 + (l2 & 15)) * CSTR +
                                       ch * 32 + (l2 >> 4) * 8);
      *(s16x8*)(dst + rf_idx(nt0 + nt, ch, l2)) = fr;
    }
  } else {
    // V transpose-stage: sT[e][m]; rows 131..143: ones at 131, zeros above.
    for (int i = tid; i < 13 * 64; i += 256) {
      const int e = D_ + (i >> 6);
      sT[(size_t)e * TSTR + (i & 63)] = (e == D_) ? (ushort)0x3F80 : (ushort)0;
    }
#pragma unroll
    for (int et = 0; et < 9; ++et) {
      const int e = et * 16 + lr;
      if (e < D_) {
        const float bval = sB[e];
#pragma unroll
        for (int r = 0; r < 4; ++r)
          sT[(size_t)e * TSTR + w * 16 + lg * 4 + r] = f2bf(acc[et][r] + bval);
      }
    }
    __syncthreads();
    const int kt0 = r0 >> 5;
    for (int i = tid; i < 2 * 9 * 64; i += 256) {
      const int ktl = i / 576;
      const int rem = i - ktl * 576;
      const int dt = rem >> 6;
      const int l2 = rem & 63;
      const s16x8 fr = *(const s16x8*)(sT + (size_t)(dt * 16 + (l2 & 15)) * TSTR +
                                       ktl * 32 + (l2 >> 4) * 8);
      *(s16x8*)(Vf + vf_idx(kt0 + ktl, dt, l2)) = fr;
    }
  }
}

// ---------------------------------------------------------------------------
// Kernel 2: MFMA flash attention. grid(512): b=id&7, q0=(id>>3)*32.
// block 256 = 4 waves, same 32 queries; wave w owns keys [512w,512w+512)
// (16 tiles of 32). ALL hot-loop loads are coalesced fragment loads.
// K double-buffered in regs; V loaded at tile start; l fused via ones-row;
// defer-max. End: single barrier, wave 0 merges 4 partials.
// ---------------------------------------------------------------------------
__global__ __launch_bounds__(256, 2) void attn_mfma(
    const ushort* __restrict__ Qf, const ushort* __restrict__ Kf,
    const ushort* __restrict__ Vf, float* __restrict__ out) {
  const int id = blockIdx.x;
  const int b = id & 7;
  const int q0 = (id >> 3) * 32;
  const int tid = threadIdx.x;
  const int w = tid >> 6;
  const int l = tid & 63;
  const int lr = l & 15;
  const int lg = l >> 4;

  __shared__ ushort sP[4][32 * PSTR];
  __shared__ float cm[3][32];
  __shared__ float cO[3][32][COSTR];

  ushort* sPw = sP[w];
  const int qnt0 = b * 128 + (q0 >> 4);

  s16x8 qf[2][5];
#pragma unroll
  for (int qt = 0; qt < 2; ++qt)
#pragma unroll
    for (int ch = 0; ch < 5; ++ch)
      qf[qt][ch] = *(const s16x8*)(Qf + rf_idx(qnt0 + qt, ch, l));

  s16x8 kA[2][5], kB[2][5];
  {
    const int knt = b * 128 + w * 32;
#pragma unroll
    for (int ch = 0; ch < 5; ++ch)
#pragma unroll
      for (int a = 0; a < 2; ++a)
        kA[a][ch] = *(const s16x8*)(Kf + rf_idx(knt + a, ch, l));
  }

  f32x4 o[2][DT];
#pragma unroll
  for (int qt = 0; qt < 2; ++qt)
#pragma unroll
    for (int dt = 0; dt < DT; ++dt) o[qt][dt] = (f32x4){0.f, 0.f, 0.f, 0.f};
  float mreg[2] = {-1e30f, -1e30f};

  auto tile_body = [&](s16x8(&KC)[2][5], s16x8(&KN)[2][5], int kt, int ktn) {
    // V fragments for this tile (coalesced; consumed at PV)
    s16x8 vf[DT];
#pragma unroll
    for (int dt = 0; dt < DT; ++dt)
      vf[dt] = *(const s16x8*)(Vf + vf_idx(b * 64 + kt, dt, l));
    // prefetch next K tile (coalesced)
    {
      const int knt = b * 128 + ktn * 2;
#pragma unroll
      for (int ch = 0; ch < 5; ++ch)
#pragma unroll
        for (int a = 0; a < 2; ++a)
          KN[a][ch] = *(const s16x8*)(Kf + rf_idx(knt + a, ch, l));
    }
    // S^T = K * Q^T (col of C = query = lane&15)
    f32x4 s[2][2];
#pragma unroll
    for (int a = 0; a < 2; ++a)
#pragma unroll
      for (int qt = 0; qt < 2; ++qt) s[a][qt] = (f32x4){0.f, 0.f, 0.f, 0.f};
#pragma unroll
    for (int ch = 0; ch < 5; ++ch) {
      s[0][0] = __builtin_amdgcn_mfma_f32_16x16x32_bf16(KC[0][ch], qf[0][ch], s[0][0], 0, 0, 0);
      s[1][0] = __builtin_amdgcn_mfma_f32_16x16x32_bf16(KC[1][ch], qf[0][ch], s[1][0], 0, 0, 0);
      s[0][1] = __builtin_amdgcn_mfma_f32_16x16x32_bf16(KC[0][ch], qf[1][ch], s[0][1], 0, 0, 0);
      s[1][1] = __builtin_amdgcn_mfma_f32_16x16x32_bf16(KC[1][ch], qf[1][ch], s[1][1], 0, 0, 0);
    }
    // online softmax (query = lane&15), defer-max; l fused via ones-row
#pragma unroll
    for (int qt = 0; qt < 2; ++qt) {
      float tm = s[0][qt][0];
#pragma unroll
      for (int a = 0; a < 2; ++a)
#pragma unroll
        for (int r = 0; r < 4; ++r) tm = fmaxf(tm, s[a][qt][r]);
      tm = fmaxf(tm, __shfl_xor(tm, 16, 64));
      tm = fmaxf(tm, __shfl_xor(tm, 32, 64));
      if (__any(tm > mreg[qt])) {
        const float mo = mreg[qt];
        const float mn = fmaxf(mo, tm);
        mreg[qt] = mn;
        const float f = __expf(mo - mn);
        float fr[4];
#pragma unroll
        for (int r = 0; r < 4; ++r) fr[r] = __shfl(f, lg * 4 + r, 64);
#pragma unroll
        for (int dt = 0; dt < DT; ++dt)
#pragma unroll
          for (int r = 0; r < 4; ++r) o[qt][dt][r] *= fr[r];
      }
      const float mcur = mreg[qt];
#pragma unroll
      for (int a = 0; a < 2; ++a) {
        const float p0 = __expf(s[a][qt][0] - mcur);
        const float p1 = __expf(s[a][qt][1] - mcur);
        const float p2 = __expf(s[a][qt][2] - mcur);
        const float p3 = __expf(s[a][qt][3] - mcur);
        uint2 u;
        u.x = bfpair(p0, p1);
        u.y = bfpair(p2, p3);
        *(uint2*)(sPw + (size_t)(qt * 16 + lr) * PSTR + a * 16 + lg * 4) = u;
      }
    }
    // PV (+ fused l at dt=8, d=131)
    const s16x8 pa0 = *(const s16x8*)(sPw + (size_t)lr * PSTR + lg * 8);
    const s16x8 pa1 = *(const s16x8*)(sPw + (size_t)(16 + lr) * PSTR + lg * 8);
#pragma unroll
    for (int dt = 0; dt < DT; ++dt) {
      o[0][dt] = __builtin_amdgcn_mfma_f32_16x16x32_bf16(pa0, vf[dt], o[0][dt], 0, 0, 0);
      o[1][dt] = __builtin_amdgcn_mfma_f32_16x16x32_bf16(pa1, vf[dt], o[1][dt], 0, 0, 0);
    }
  };

  for (int i = 0; i < 8; ++i) {
    const int kt = w * 16 + 2 * i;
    tile_body(kA, kB, kt, kt + 1);
    tile_body(kB, kA, kt + 1, (i < 7) ? kt + 2 : kt + 1);
  }

  // ---- cross-wave merge ----
  if (w > 0) {
    if (lg == 0) {
      cm[w - 1][lr] = mreg[0];
      cm[w - 1][16 + lr] = mreg[1];
    }
#pragma unroll
    for (int qt = 0; qt < 2; ++qt)
#pragma unroll
      for (int dt = 0; dt < DT; ++dt)
#pragma unroll
        for (int r = 0; r < 4; ++r)
          cO[w - 1][qt * 16 + lg * 4 + r][dt * 16 + lr] = o[qt][dt][r];
  }
  __syncthreads();
  if (w == 0) {
#pragma unroll
    for (int qt = 0; qt < 2; ++qt) {
      const int qq = qt * 16 + lr;
      const float m1 = cm[0][qq], m2 = cm[1][qq], m3 = cm[2][qq];
      const float M = fmaxf(fmaxf(mreg[qt], m1), fmaxf(m2, m3));
      const float e0 = __expf(mreg[qt] - M);
      const float e1 = __expf(m1 - M);
      const float e2 = __expf(m2 - M);
      const float e3 = __expf(m3 - M);
      float er0[4], er1[4], er2[4], er3[4];
#pragma unroll
      for (int r = 0; r < 4; ++r) {
        er0[r] = __shfl(e0, lg * 4 + r, 64);
        er1[r] = __shfl(e1, lg * 4 + r, 64);
        er2[r] = __shfl(e2, lg * 4 + r, 64);
        er3[r] = __shfl(e3, lg * 4 + r, 64);
      }
      float l8[4];
#pragma unroll
      for (int r = 0; r < 4; ++r) {
        const int row = qt * 16 + lg * 4 + r;
        l8[r] = o[qt][8][r] * er0[r] + cO[0][row][128 + lr] * er1[r] +
                cO[1][row][128 + lr] * er2[r] + cO[2][row][128 + lr] * er3[r];
      }
      float ir[4];
#pragma unroll
      for (int r = 0; r < 4; ++r)
        ir[r] = 1.f / __shfl(l8[r], (l & 48) + 3, 64);
#pragma unroll
      for (int dt = 0; dt < DT; ++dt) {
        const int d = dt * 16 + lr;
        if (d < D_) {
#pragma unroll
          for (int r = 0; r < 4; ++r) {
            const int row = qt * 16 + lg * 4 + r;
            const float val = (dt == 8 ? l8[r]
                                       : o[qt][dt][r] * er0[r] +
                                             cO[0][row][d] * er1[r] +
                                             cO[1][row][d] * er2[r] +
                                             cO[2][row][d] * er3[r]);
            out[((size_t)b * N_ + q0 + row) * D_ + d] = val * ir[r];
          }
        }
      }
    }
  }
}

extern "C" void kernel_launch(void* const* d_in, const int* in_sizes, int n_in,
                              void* d_out, int out_size, void* d_ws,
                              size_t ws_size, hipStream_t stream) {
  const float* q = (const float*)d_in[0];
  const float* k = (const float*)d_in[1];
  const float* v = (const float*)d_in[2];
  const float* Wq = (const float*)d_in[3];
  const float* bq = (const float*)d_in[4];
  const float* Wk = (const float*)d_in[5];
  const float* bk = (const float*)d_in[6];
  const float* Wv = (const float*)d_in[7];
  const float* bv = (const float*)d_in[8];
  float* out = (float*)d_out;

  // ws layout (bytes):
  //   Qf  [1024 nt][5][64][8]u16 @ 0           (5,242,880)
  //   Kf  same                   @ 5,242,880   (5,242,880)
  //   Vf  [512 ktg][9][64][8]u16 @ 10,485,760  (4,718,592)
  //   Whl [3][2][9][5][64][8]u16 @ 15,204,352  (276,480)
  char* wsb = (char*)d_ws;
  ushort* Qf = (ushort*)(wsb);
  ushort* Kf = (ushort*)(wsb + 5242880);
  ushort* Vf = (ushort*)(wsb + 10485760);
  ushort* Whl = (ushort*)(wsb + 15204352);

  hipLaunchKernelGGL(cast_w_kernel, dim3(3), dim3(256), 0, stream, Wq, Wk, Wv,
                     Whl);
  hipLaunchKernelGGL(proj_gemm, dim3(256, 3), dim3(256), 0, stream, q, k, v,
                     bq, bk, bv, Whl, Qf, Kf, Vf);
  hipLaunchKernelGGL(attn_mfma, dim3(512), dim3(256), 0, stream, Qf, Kf, Vf,
                     out);
}